// Round 9
// baseline (396.780 us; speedup 1.0000x reference)
//
#include <hip/hip_runtime.h>
#include <hip/hip_bf16.h>

#define T_TOK 2048
#define HID   1024
#define EXP   64
#define TOPK  8
#define IMED  512

typedef __bf16 bf16x8 __attribute__((ext_vector_type(8)));
typedef float f32x4 __attribute__((ext_vector_type(4)));
typedef unsigned short ushortx8 __attribute__((ext_vector_type(8)));
typedef unsigned short ushortx4 __attribute__((ext_vector_type(4)));

__constant__ int kShifts[8] = {0, 16, 4, 20, 8, 24, 12, 28};

__device__ __forceinline__ void async16(const void* g, void* l) {
  __builtin_amdgcn_global_load_lds((const __attribute__((address_space(1))) void*)g,
                                   (__attribute__((address_space(3))) void*)l, 16, 0, 0);
}

// round-to-nearest-even f32 -> bf16 bits
__device__ __forceinline__ unsigned short f2bf(float f) {
  unsigned u = __builtin_bit_cast(unsigned, f);
  unsigned r = (u + 0x7fffu + ((u >> 16) & 1u)) >> 16;
  return (unsigned short)r;
}

__device__ __forceinline__ float bf2f(unsigned short b) {
  unsigned u = ((unsigned)b) << 16;
  return __builtin_bit_cast(float, u);
}

// ---------------- Routing: 256 thr/token, LDS x-row, fused bf16 cast (verified R4/R8) ----------------
__global__ __launch_bounds__(256) void routing_kernel(
    const float* __restrict__ x, const float* __restrict__ gate_w,
    int* __restrict__ counts, int* __restrict__ tok_list,
    int* __restrict__ hslot_list, float* __restrict__ cw_list,
    unsigned short* __restrict__ xbf) {
  const int t = blockIdx.x;
  const int tid = threadIdx.x;
  __shared__ float xs[HID];
  __shared__ float part[64][4];

  float4 v = reinterpret_cast<const float4*>(x + (size_t)t * HID)[tid];
  reinterpret_cast<float4*>(xs)[tid] = v;
  ushortx4 o;
  o[0] = f2bf(v.x); o[1] = f2bf(v.y); o[2] = f2bf(v.z); o[3] = f2bf(v.w);
  *reinterpret_cast<ushortx4*>(xbf + (size_t)t * HID + tid * 4) = o;
  __syncthreads();

  const int e = tid >> 2, seg = tid & 3;
  const float4* gp = reinterpret_cast<const float4*>(gate_w + (size_t)e * HID);
  const float4* xp = reinterpret_cast<const float4*>(xs);
  float acc = 0.f;
#pragma unroll 8
  for (int i = 0; i < 64; ++i) {
    float4 a = xp[i * 4 + seg];
    float4 b = gp[i * 4 + seg];
    acc = fmaf(a.x, b.x, acc);
    acc = fmaf(a.y, b.y, acc);
    acc = fmaf(a.z, b.z, acc);
    acc = fmaf(a.w, b.w, acc);
  }
  part[e][seg] = acc;
  __syncthreads();

  if (tid < 64) {
    float4 p = reinterpret_cast<const float4*>(part)[tid];
    float lg = (p.x + p.y) + (p.z + p.w);

    float m = lg;
    for (int off = 32; off; off >>= 1) m = fmaxf(m, __shfl_xor(m, off));
    float pe = expf(lg - m);
    float s = pe;
    for (int off = 32; off; off >>= 1) s += __shfl_xor(s, off);
    float prob = pe / s;

    float pcur = prob;
    float myv = 0.f;
    int myi = -1;
    float tsum = 0.f;
    for (int k = 0; k < TOPK; ++k) {
      float vv = pcur;
      int idx = tid;
      for (int off = 32; off; off >>= 1) {
        float ov = __shfl_xor(vv, off);
        int oi = __shfl_xor(idx, off);
        if (ov > vv || (ov == vv && oi < idx)) { vv = ov; idx = oi; }
      }
      tsum += vv;
      if (tid == k) { myv = vv; myi = idx; }
      if (tid == idx) pcur = -1.f;
    }

    if (tid < TOPK) {
      float cw = myv / tsum;
      int ex = myi;
      int slot = atomicAdd(&counts[ex], 1);
      tok_list[ex * T_TOK + slot] = t;
      hslot_list[ex * T_TOK + slot] = t * TOPK + tid;
      cw_list[ex * T_TOK + slot] = cw;
    }
  }
}

// ---------------- AWQ dequant -> bf16, transposed to [n][k] (verified R2/R3/R8) ----------------
__global__ __launch_bounds__(256) void dequant_kernel(
    const int* __restrict__ qw, const int* __restrict__ qz,
    const float* __restrict__ sc, unsigned short* __restrict__ outw,
    int K, int C) {
  __shared__ unsigned short tile[128][72];
  const int kk = threadIdx.x & 63;
  const int cc4 = threadIdx.x >> 6;  // 0..3
  const int k = blockIdx.y * 64 + kk;
  const int c0 = blockIdx.x * 16 + cc4 * 4;
  const int g = k >> 7;
  const int N = C * 8;

  int4 q4 = *reinterpret_cast<const int4*>(qw + (size_t)k * C + c0);
  int4 z4 = *reinterpret_cast<const int4*>(qz + (size_t)g * C + c0);
  const float* sp = sc + (size_t)g * N + (size_t)c0 * 8;
  const int qs[4] = {q4.x, q4.y, q4.z, q4.w};
  const int zs[4] = {z4.x, z4.y, z4.z, z4.w};
#pragma unroll
  for (int it = 0; it < 4; ++it) {
    const unsigned q = (unsigned)qs[it];
    const unsigned z = (unsigned)zs[it];
    float4 s0 = *reinterpret_cast<const float4*>(sp + it * 8);
    float4 s1 = *reinterpret_cast<const float4*>(sp + it * 8 + 4);
    float sv[8] = {s0.x, s0.y, s0.z, s0.w, s1.x, s1.y, s1.z, s1.w};
#pragma unroll
    for (int j = 0; j < 8; ++j) {
      const int sh = kShifts[j];
      const float val = (float)((int)((q >> sh) & 15u) - (int)((z >> sh) & 15u));
      tile[(cc4 * 4 + it) * 8 + j][kk] = f2bf(val * sv[j]);
    }
  }
  __syncthreads();
  const size_t kbase = (size_t)blockIdx.y * 64;
#pragma unroll
  for (int it = 0; it < 4; ++it) {
    const int slot = threadIdx.x + 256 * it;
    const int row = slot >> 3, seg = slot & 7;
    const int n = blockIdx.x * 128 + row;
    *reinterpret_cast<ushortx8*>(outw + (size_t)n * K + kbase + seg * 8) =
        *reinterpret_cast<const ushortx8*>(&tile[row][seg * 8]);
  }
}

// ---------------- MFMA GEMM1 (quad-buffered, 64-K per barrier): h = silu(x.w1^T)*cw ----------------
__global__ __launch_bounds__(256) void mfma_gemm1(
    const unsigned short* __restrict__ xbf, const unsigned short* __restrict__ dqw1,
    const int* __restrict__ counts, const int* __restrict__ tok_list,
    const int* __restrict__ hslot_list, const float* __restrict__ cw_list,
    unsigned short* __restrict__ h_buf) {
  const int e = blockIdx.z;
  const int n_e = counts[e];
  const int t0 = blockIdx.y * 128;
  if (t0 >= n_e) return;
  const int ntile = blockIdx.x;  // 0..3
  const int tid = threadIdx.x;
  const int wave = tid >> 6, lane = tid & 63;
  const int wm = wave & 1, wn = wave >> 1;

  __shared__ unsigned short As[4][128 * 32];  // 4 x 8KB
  __shared__ unsigned short Bs[4][128 * 32];  // 4 x 8KB (total 64KB)

  const int rsub = lane >> 2;
  const int csub = lane & 3;
  const int ra0 = t0 + wave * 32 + rsub;
  const int ra1 = ra0 + 16;
  const int ta0 = tok_list[e * T_TOK + min(ra0, n_e - 1)];
  const int ta1 = tok_list[e * T_TOK + min(ra1, n_e - 1)];
  const char* ga0 = (const char*)(xbf + (size_t)ta0 * HID) + csub * 16;
  const char* ga1 = (const char*)(xbf + (size_t)ta1 * HID) + csub * 16;
  const int nb = e * IMED + ntile * 128 + wave * 32 + rsub;
  const char* gb0 = (const char*)(dqw1 + (size_t)nb * HID) + csub * 16;
  const char* gb1 = gb0 + 16 * HID * 2;

  f32x4 acc[4][4];
#pragma unroll
  for (int i = 0; i < 4; ++i)
#pragma unroll
    for (int j = 0; j < 4; ++j) acc[i][j] = (f32x4){0.f, 0.f, 0.f, 0.f};

  const int fr = lane & 15, fq = lane >> 4;

  // stage one 32-K tile into buffer q (R8-identical pattern); advances pointers by 64B
  auto stage = [&](int q) {
    char* la = (char*)&As[q][0] + wave * 2048;
    char* lb = (char*)&Bs[q][0] + wave * 2048;
    async16(ga0, la);
    async16(ga1, la + 1024);
    async16(gb0, lb);
    async16(gb1, lb + 1024);
    ga0 += 64; ga1 += 64; gb0 += 64; gb1 += 64;
  };

  stage(0);
  stage(1);
  int p = 0;  // active buffer pair {2p, 2p+1}
  for (int it = 0; it < 16; ++it) {  // 16 iters x 64-K
    __syncthreads();  // drains async into pair p
    if (it + 1 < 16) { stage((p ^ 1) * 2); stage((p ^ 1) * 2 + 1); }
#pragma unroll
    for (int kk = 0; kk < 2; ++kk) {
      const int q = p * 2 + kk;
      bf16x8 af[4], bfr[4];
#pragma unroll
      for (int i = 0; i < 4; ++i)
        af[i] = *reinterpret_cast<const bf16x8*>(&As[q][(wm * 64 + i * 16 + fr) * 32 + fq * 8]);
#pragma unroll
      for (int j = 0; j < 4; ++j)
        bfr[j] = *reinterpret_cast<const bf16x8*>(&Bs[q][(wn * 64 + j * 16 + fr) * 32 + fq * 8]);
#pragma unroll
      for (int i = 0; i < 4; ++i)
#pragma unroll
        for (int j = 0; j < 4; ++j)
          acc[i][j] = __builtin_amdgcn_mfma_f32_16x16x32_bf16(af[i], bfr[j], acc[i][j], 0, 0, 0);
    }
    p ^= 1;
  }

  // epilogue: C/D map col = lane&15, row = (lane>>4)*4 + reg
#pragma unroll
  for (int i = 0; i < 4; ++i) {
#pragma unroll
    for (int r = 0; r < 4; ++r) {
      const int grow = t0 + wm * 64 + i * 16 + fq * 4 + r;
      if (grow < n_e) {
        const float cw = cw_list[e * T_TOK + grow];
        const int hs = hslot_list[e * T_TOK + grow];
        unsigned short* dst = h_buf + (size_t)hs * IMED + ntile * 128 + wn * 64 + fr;
#pragma unroll
        for (int j = 0; j < 4; ++j) {
          const float v = acc[i][j][r];
          dst[j * 16] = f2bf((v / (1.f + expf(-v))) * cw);
        }
      }
    }
  }
}

// ---------------- MFMA GEMM2 (quad-buffered, 64-K per barrier): p_buf = h . w2^T ----------------
__global__ __launch_bounds__(256) void mfma_gemm2(
    const unsigned short* __restrict__ h_buf, const unsigned short* __restrict__ dqw2,
    const int* __restrict__ counts, const int* __restrict__ hslot_list,
    unsigned short* __restrict__ p_buf) {
  const int e = blockIdx.z;
  const int n_e = counts[e];
  const int t0 = blockIdx.y * 128;
  if (t0 >= n_e) return;
  const int ntile = blockIdx.x;  // 0..7
  const int tid = threadIdx.x;
  const int wave = tid >> 6, lane = tid & 63;
  const int wm = wave & 1, wn = wave >> 1;

  __shared__ unsigned short As[4][128 * 32];
  __shared__ unsigned short Bs[4][128 * 32];

  const int rsub = lane >> 2;
  const int csub = lane & 3;
  const int ra0 = t0 + wave * 32 + rsub;
  const int ra1 = ra0 + 16;
  const int ha0 = hslot_list[e * T_TOK + min(ra0, n_e - 1)];
  const int ha1 = hslot_list[e * T_TOK + min(ra1, n_e - 1)];
  const char* ga0 = (const char*)(h_buf + (size_t)ha0 * IMED) + csub * 16;
  const char* ga1 = (const char*)(h_buf + (size_t)ha1 * IMED) + csub * 16;
  const int nb = e * HID + ntile * 128 + wave * 32 + rsub;
  const char* gb0 = (const char*)(dqw2 + (size_t)nb * IMED) + csub * 16;
  const char* gb1 = gb0 + 16 * IMED * 2;

  f32x4 acc[4][4];
#pragma unroll
  for (int i = 0; i < 4; ++i)
#pragma unroll
    for (int j = 0; j < 4; ++j) acc[i][j] = (f32x4){0.f, 0.f, 0.f, 0.f};

  const int fr = lane & 15, fq = lane >> 4;

  auto stage = [&](int q) {
    char* la = (char*)&As[q][0] + wave * 2048;
    char* lb = (char*)&Bs[q][0] + wave * 2048;
    async16(ga0, la);
    async16(ga1, la + 1024);
    async16(gb0, lb);
    async16(gb1, lb + 1024);
    ga0 += 64; ga1 += 64; gb0 += 64; gb1 += 64;
  };

  stage(0);
  stage(1);
  int p = 0;
  for (int it = 0; it < 8; ++it) {  // 8 iters x 64-K
    __syncthreads();
    if (it + 1 < 8) { stage((p ^ 1) * 2); stage((p ^ 1) * 2 + 1); }
#pragma unroll
    for (int kk = 0; kk < 2; ++kk) {
      const int q = p * 2 + kk;
      bf16x8 af[4], bfr[4];
#pragma unroll
      for (int i = 0; i < 4; ++i)
        af[i] = *reinterpret_cast<const bf16x8*>(&As[q][(wm * 64 + i * 16 + fr) * 32 + fq * 8]);
#pragma unroll
      for (int j = 0; j < 4; ++j)
        bfr[j] = *reinterpret_cast<const bf16x8*>(&Bs[q][(wn * 64 + j * 16 + fr) * 32 + fq * 8]);
#pragma unroll
      for (int i = 0; i < 4; ++i)
#pragma unroll
        for (int j = 0; j < 4; ++j)
          acc[i][j] = __builtin_amdgcn_mfma_f32_16x16x32_bf16(af[i], bfr[j], acc[i][j], 0, 0, 0);
    }
    p ^= 1;
  }

  // epilogue: plain bf16 partial stores (no atomics); every (hslot, col) written once
#pragma unroll
  for (int i = 0; i < 4; ++i) {
#pragma unroll
    for (int r = 0; r < 4; ++r) {
      const int grow = t0 + wm * 64 + i * 16 + fq * 4 + r;
      if (grow < n_e) {
        const int hs = hslot_list[e * T_TOK + grow];
        unsigned short* dst = p_buf + (size_t)hs * HID + ntile * 128 + wn * 64 + fr;
#pragma unroll
        for (int j = 0; j < 4; ++j) dst[j * 16] = f2bf(acc[i][j][r]);
      }
    }
  }
}

// ---------------- Reduce 8 partials per token -> out (fp32, verified R3/R8) ----------------
__global__ __launch_bounds__(256) void reduce_kernel(const unsigned short* __restrict__ p_buf,
                                                     float* __restrict__ out) {
  const int idx = blockIdx.x * 256 + threadIdx.x;
  const int t = idx >> 7;
  const int c0 = (idx & 127) * 8;
  float s[8] = {0.f, 0.f, 0.f, 0.f, 0.f, 0.f, 0.f, 0.f};
#pragma unroll
  for (int k = 0; k < TOPK; ++k) {
    ushortx8 v = *reinterpret_cast<const ushortx8*>(p_buf + ((size_t)t * TOPK + k) * HID + c0);
#pragma unroll
    for (int j = 0; j < 8; ++j) s[j] += bf2f(v[j]);
  }
  float* dst = out + (size_t)t * HID + c0;
  *reinterpret_cast<float4*>(dst) = make_float4(s[0], s[1], s[2], s[3]);
  *reinterpret_cast<float4*>(dst + 4) = make_float4(s[4], s[5], s[6], s[7]);
}

extern "C" void kernel_launch(void* const* d_in, const int* in_sizes, int n_in,
                              void* d_out, int out_size, void* d_ws, size_t ws_size,
                              hipStream_t stream) {
  const float* x      = (const float*)d_in[0];
  const float* gate_w = (const float*)d_in[1];
  const int*   qw1    = (const int*)d_in[2];
  const int*   qz1    = (const int*)d_in[3];
  const float* sc1    = (const float*)d_in[4];
  const int*   qw2    = (const int*)d_in[5];
  const int*   qz2    = (const int*)d_in[6];
  const float* sc2    = (const float*)d_in[7];
  float* out = (float*)d_out;

  // workspace layout (R3/R8-verified; p_buf aliases dqw1, dead after gemm1)
  char* ws = (char*)d_ws;
  int* counts           = (int*)(ws);                        // 256 B
  int* tok_list         = (int*)(ws + 256);                  // 512 KB
  int* hslot_list       = (int*)(ws + 524544);               // 512 KB
  float* cw_list        = (float*)(ws + 1048832);            // 512 KB
  unsigned short* h_buf = (unsigned short*)(ws + 1573120);   // 16.8 MB
  unsigned short* xbf   = (unsigned short*)(ws + 18350336);  // 4.2 MB
  unsigned short* dqw1  = (unsigned short*)(ws + 22544640);  // 67 MB
  unsigned short* dqw2  = (unsigned short*)(ws + 89653504);  // 67 MB
  unsigned short* p_buf = (unsigned short*)(ws + 22544640);  // 33.6 MB (aliases dqw1)

  hipMemsetAsync(counts, 0, 256, stream);

  routing_kernel<<<T_TOK, 256, 0, stream>>>(x, gate_w, counts, tok_list, hslot_list, cw_list, xbf);
  dequant_kernel<<<dim3(4096 / 16, 1024 / 64), 256, 0, stream>>>(qw1, qz1, sc1, dqw1, HID, 4096);
  dequant_kernel<<<dim3(8192 / 16, 512 / 64), 256, 0, stream>>>(qw2, qz2, sc2, dqw2, IMED, 8192);

  mfma_gemm1<<<dim3(IMED / 128, T_TOK / 128, EXP), 256, 0, stream>>>(
      xbf, dqw1, counts, tok_list, hslot_list, cw_list, h_buf);
  mfma_gemm2<<<dim3(HID / 128, T_TOK / 128, EXP), 256, 0, stream>>>(
      h_buf, dqw2, counts, hslot_list, p_buf);
  reduce_kernel<<<(T_TOK * HID / 8) / 256, 256, 0, stream>>>(p_buf, out);
}

// Round 10
// 321.169 us; speedup vs baseline: 1.2354x; 1.2354x over previous
//
#include <hip/hip_runtime.h>
#include <hip/hip_bf16.h>

#define T_TOK 2048
#define HID   1024
#define EXP   64
#define TOPK  8
#define IMED  512

typedef __bf16 bf16x8 __attribute__((ext_vector_type(8)));
typedef float f32x4 __attribute__((ext_vector_type(4)));
typedef unsigned short ushortx8 __attribute__((ext_vector_type(8)));
typedef unsigned short ushortx4 __attribute__((ext_vector_type(4)));

__constant__ int kShifts[8] = {0, 16, 4, 20, 8, 24, 12, 28};

__device__ __forceinline__ void async16(const void* g, void* l) {
  __builtin_amdgcn_global_load_lds((const __attribute__((address_space(1))) void*)g,
                                   (__attribute__((address_space(3))) void*)l, 16, 0, 0);
}

// round-to-nearest-even f32 -> bf16 bits
__device__ __forceinline__ unsigned short f2bf(float f) {
  unsigned u = __builtin_bit_cast(unsigned, f);
  unsigned r = (u + 0x7fffu + ((u >> 16) & 1u)) >> 16;
  return (unsigned short)r;
}

__device__ __forceinline__ float bf2f(unsigned short b) {
  unsigned u = ((unsigned)b) << 16;
  return __builtin_bit_cast(float, u);
}

// ---------------- Routing: 256 thr/token, LDS x-row, fused bf16 cast (verified R4/R8) ----------------
__global__ __launch_bounds__(256) void routing_kernel(
    const float* __restrict__ x, const float* __restrict__ gate_w,
    int* __restrict__ counts, int* __restrict__ tok_list,
    int* __restrict__ hslot_list, float* __restrict__ cw_list,
    unsigned short* __restrict__ xbf) {
  const int t = blockIdx.x;
  const int tid = threadIdx.x;
  __shared__ float xs[HID];
  __shared__ float part[64][4];

  float4 v = reinterpret_cast<const float4*>(x + (size_t)t * HID)[tid];
  reinterpret_cast<float4*>(xs)[tid] = v;
  ushortx4 o;
  o[0] = f2bf(v.x); o[1] = f2bf(v.y); o[2] = f2bf(v.z); o[3] = f2bf(v.w);
  *reinterpret_cast<ushortx4*>(xbf + (size_t)t * HID + tid * 4) = o;
  __syncthreads();

  const int e = tid >> 2, seg = tid & 3;
  const float4* gp = reinterpret_cast<const float4*>(gate_w + (size_t)e * HID);
  const float4* xp = reinterpret_cast<const float4*>(xs);
  float acc = 0.f;
#pragma unroll 8
  for (int i = 0; i < 64; ++i) {
    float4 a = xp[i * 4 + seg];
    float4 b = gp[i * 4 + seg];
    acc = fmaf(a.x, b.x, acc);
    acc = fmaf(a.y, b.y, acc);
    acc = fmaf(a.z, b.z, acc);
    acc = fmaf(a.w, b.w, acc);
  }
  part[e][seg] = acc;
  __syncthreads();

  if (tid < 64) {
    float4 p = reinterpret_cast<const float4*>(part)[tid];
    float lg = (p.x + p.y) + (p.z + p.w);

    float m = lg;
    for (int off = 32; off; off >>= 1) m = fmaxf(m, __shfl_xor(m, off));
    float pe = expf(lg - m);
    float s = pe;
    for (int off = 32; off; off >>= 1) s += __shfl_xor(s, off);
    float prob = pe / s;

    float pcur = prob;
    float myv = 0.f;
    int myi = -1;
    float tsum = 0.f;
    for (int k = 0; k < TOPK; ++k) {
      float vv = pcur;
      int idx = tid;
      for (int off = 32; off; off >>= 1) {
        float ov = __shfl_xor(vv, off);
        int oi = __shfl_xor(idx, off);
        if (ov > vv || (ov == vv && oi < idx)) { vv = ov; idx = oi; }
      }
      tsum += vv;
      if (tid == k) { myv = vv; myi = idx; }
      if (tid == idx) pcur = -1.f;
    }

    if (tid < TOPK) {
      float cw = myv / tsum;
      int ex = myi;
      int slot = atomicAdd(&counts[ex], 1);
      tok_list[ex * T_TOK + slot] = t;
      hslot_list[ex * T_TOK + slot] = t * TOPK + tid;
      cw_list[ex * T_TOK + slot] = cw;
    }
  }
}

// ---------------- AWQ dequant -> bf16, transposed to [n][k] (verified R2/R3/R8) ----------------
__global__ __launch_bounds__(256) void dequant_kernel(
    const int* __restrict__ qw, const int* __restrict__ qz,
    const float* __restrict__ sc, unsigned short* __restrict__ outw,
    int K, int C) {
  __shared__ unsigned short tile[128][72];
  const int kk = threadIdx.x & 63;
  const int cc4 = threadIdx.x >> 6;  // 0..3
  const int k = blockIdx.y * 64 + kk;
  const int c0 = blockIdx.x * 16 + cc4 * 4;
  const int g = k >> 7;
  const int N = C * 8;

  int4 q4 = *reinterpret_cast<const int4*>(qw + (size_t)k * C + c0);
  int4 z4 = *reinterpret_cast<const int4*>(qz + (size_t)g * C + c0);
  const float* sp = sc + (size_t)g * N + (size_t)c0 * 8;
  const int qs[4] = {q4.x, q4.y, q4.z, q4.w};
  const int zs[4] = {z4.x, z4.y, z4.z, z4.w};
#pragma unroll
  for (int it = 0; it < 4; ++it) {
    const unsigned q = (unsigned)qs[it];
    const unsigned z = (unsigned)zs[it];
    float4 s0 = *reinterpret_cast<const float4*>(sp + it * 8);
    float4 s1 = *reinterpret_cast<const float4*>(sp + it * 8 + 4);
    float sv[8] = {s0.x, s0.y, s0.z, s0.w, s1.x, s1.y, s1.z, s1.w};
#pragma unroll
    for (int j = 0; j < 8; ++j) {
      const int sh = kShifts[j];
      const float val = (float)((int)((q >> sh) & 15u) - (int)((z >> sh) & 15u));
      tile[(cc4 * 4 + it) * 8 + j][kk] = f2bf(val * sv[j]);
    }
  }
  __syncthreads();
  const size_t kbase = (size_t)blockIdx.y * 64;
#pragma unroll
  for (int it = 0; it < 4; ++it) {
    const int slot = threadIdx.x + 256 * it;
    const int row = slot >> 3, seg = slot & 7;
    const int n = blockIdx.x * 128 + row;
    *reinterpret_cast<ushortx8*>(outw + (size_t)n * K + kbase + seg * 8) =
        *reinterpret_cast<const ushortx8*>(&tile[row][seg * 8]);
  }
}

// ---------------- MFMA GEMM1, M-tile 64 (4 blocks/CU live), dbuf BK=32 ----------------
// h[hslot, i] = silu(x . w1^T) * cw.  Waves 2x2, wave tile 32x64, acc[2][4].
__global__ __launch_bounds__(256) void mfma_gemm1(
    const unsigned short* __restrict__ xbf, const unsigned short* __restrict__ dqw1,
    const int* __restrict__ counts, const int* __restrict__ tok_list,
    const int* __restrict__ hslot_list, const float* __restrict__ cw_list,
    unsigned short* __restrict__ h_buf) {
  const int e = blockIdx.z;
  const int n_e = counts[e];
  const int t0 = blockIdx.y * 64;
  if (t0 >= n_e) return;
  const int ntile = blockIdx.x;  // 0..3
  const int tid = threadIdx.x;
  const int wave = tid >> 6, lane = tid & 63;
  const int wm = wave & 1, wn = wave >> 1;

  __shared__ unsigned short As[2][64 * 32];   // 2 x 4KB
  __shared__ unsigned short Bs[2][128 * 32];  // 2 x 8KB (total 24KB)

  // A staging: wave-uniform base + lane*16B. lane -> row wave*16 + (lane>>2), col (lane&3)*16B
  const int arow = wave * 16 + (lane >> 2);
  const int bcol = (lane & 3) * 16;  // byte offset within 64B row
  const int ta = tok_list[e * T_TOK + min(t0 + arow, n_e - 1)];
  const char* ga = (const char*)(xbf + (size_t)ta * HID) + bcol;
  // B staging: rows nbase + {arow, 64+arow}
  const int nb = e * IMED + ntile * 128 + arow;
  const char* gb0 = (const char*)(dqw1 + (size_t)nb * HID) + bcol;
  const char* gb1 = gb0 + (size_t)64 * HID * 2;

  f32x4 acc[2][4];
#pragma unroll
  for (int i = 0; i < 2; ++i)
#pragma unroll
    for (int j = 0; j < 4; ++j) acc[i][j] = (f32x4){0.f, 0.f, 0.f, 0.f};

  const int fr = lane & 15, fq = lane >> 4;

  auto stage = [&](int b) {
    char* la = (char*)&As[b][0] + wave * 1024;
    char* lb = (char*)&Bs[b][0] + wave * 1024;
    async16(ga, la);
    async16(gb0, lb);
    async16(gb1, lb + 4096);
    ga += 64; gb0 += 64; gb1 += 64;
  };

  stage(0);
  int p = 0;
  for (int k0 = 0; k0 < HID; k0 += 32) {
    __syncthreads();  // drains async into buf p
    if (k0 + 32 < HID) stage(p ^ 1);
    bf16x8 af[2], bfr[4];
#pragma unroll
    for (int i = 0; i < 2; ++i)
      af[i] = *reinterpret_cast<const bf16x8*>(&As[p][(wm * 32 + i * 16 + fr) * 32 + fq * 8]);
#pragma unroll
    for (int j = 0; j < 4; ++j)
      bfr[j] = *reinterpret_cast<const bf16x8*>(&Bs[p][(wn * 64 + j * 16 + fr) * 32 + fq * 8]);
#pragma unroll
    for (int i = 0; i < 2; ++i)
#pragma unroll
      for (int j = 0; j < 4; ++j)
        acc[i][j] = __builtin_amdgcn_mfma_f32_16x16x32_bf16(af[i], bfr[j], acc[i][j], 0, 0, 0);
    p ^= 1;
  }

  // epilogue: C/D map col = lane&15, row = (lane>>4)*4 + reg
#pragma unroll
  for (int i = 0; i < 2; ++i) {
#pragma unroll
    for (int r = 0; r < 4; ++r) {
      const int grow = t0 + wm * 32 + i * 16 + fq * 4 + r;
      if (grow < n_e) {
        const float cw = cw_list[e * T_TOK + grow];
        const int hs = hslot_list[e * T_TOK + grow];
        unsigned short* dst = h_buf + (size_t)hs * IMED + ntile * 128 + wn * 64 + fr;
#pragma unroll
        for (int j = 0; j < 4; ++j) {
          const float v = acc[i][j][r];
          dst[j * 16] = f2bf((v / (1.f + expf(-v))) * cw);
        }
      }
    }
  }
}

// ---------------- MFMA GEMM2, M-tile 64, dbuf BK=32: p_buf = h . w2^T ----------------
__global__ __launch_bounds__(256) void mfma_gemm2(
    const unsigned short* __restrict__ h_buf, const unsigned short* __restrict__ dqw2,
    const int* __restrict__ counts, const int* __restrict__ hslot_list,
    unsigned short* __restrict__ p_buf) {
  const int e = blockIdx.z;
  const int n_e = counts[e];
  const int t0 = blockIdx.y * 64;
  if (t0 >= n_e) return;
  const int ntile = blockIdx.x;  // 0..7
  const int tid = threadIdx.x;
  const int wave = tid >> 6, lane = tid & 63;
  const int wm = wave & 1, wn = wave >> 1;

  __shared__ unsigned short As[2][64 * 32];
  __shared__ unsigned short Bs[2][128 * 32];

  const int arow = wave * 16 + (lane >> 2);
  const int bcol = (lane & 3) * 16;
  const int ha = hslot_list[e * T_TOK + min(t0 + arow, n_e - 1)];
  const char* ga = (const char*)(h_buf + (size_t)ha * IMED) + bcol;
  const int nb = e * HID + ntile * 128 + arow;
  const char* gb0 = (const char*)(dqw2 + (size_t)nb * IMED) + bcol;
  const char* gb1 = gb0 + (size_t)64 * IMED * 2;

  f32x4 acc[2][4];
#pragma unroll
  for (int i = 0; i < 2; ++i)
#pragma unroll
    for (int j = 0; j < 4; ++j) acc[i][j] = (f32x4){0.f, 0.f, 0.f, 0.f};

  const int fr = lane & 15, fq = lane >> 4;

  auto stage = [&](int b) {
    char* la = (char*)&As[b][0] + wave * 1024;
    char* lb = (char*)&Bs[b][0] + wave * 1024;
    async16(ga, la);
    async16(gb0, lb);
    async16(gb1, lb + 4096);
    ga += 64; gb0 += 64; gb1 += 64;
  };

  stage(0);
  int p = 0;
  for (int k0 = 0; k0 < IMED; k0 += 32) {
    __syncthreads();
    if (k0 + 32 < IMED) stage(p ^ 1);
    bf16x8 af[2], bfr[4];
#pragma unroll
    for (int i = 0; i < 2; ++i)
      af[i] = *reinterpret_cast<const bf16x8*>(&As[p][(wm * 32 + i * 16 + fr) * 32 + fq * 8]);
#pragma unroll
    for (int j = 0; j < 4; ++j)
      bfr[j] = *reinterpret_cast<const bf16x8*>(&Bs[p][(wn * 64 + j * 16 + fr) * 32 + fq * 8]);
#pragma unroll
    for (int i = 0; i < 2; ++i)
#pragma unroll
      for (int j = 0; j < 4; ++j)
        acc[i][j] = __builtin_amdgcn_mfma_f32_16x16x32_bf16(af[i], bfr[j], acc[i][j], 0, 0, 0);
    p ^= 1;
  }

  // epilogue: plain bf16 partial stores (no atomics); every (hslot, col) written once
#pragma unroll
  for (int i = 0; i < 2; ++i) {
#pragma unroll
    for (int r = 0; r < 4; ++r) {
      const int grow = t0 + wm * 32 + i * 16 + fq * 4 + r;
      if (grow < n_e) {
        const int hs = hslot_list[e * T_TOK + grow];
        unsigned short* dst = p_buf + (size_t)hs * HID + ntile * 128 + wn * 64 + fr;
#pragma unroll
        for (int j = 0; j < 4; ++j) dst[j * 16] = f2bf(acc[i][j][r]);
      }
    }
  }
}

// ---------------- Reduce 8 partials per token -> out (fp32, verified R3/R8) ----------------
__global__ __launch_bounds__(256) void reduce_kernel(const unsigned short* __restrict__ p_buf,
                                                     float* __restrict__ out) {
  const int idx = blockIdx.x * 256 + threadIdx.x;
  const int t = idx >> 7;
  const int c0 = (idx & 127) * 8;
  float s[8] = {0.f, 0.f, 0.f, 0.f, 0.f, 0.f, 0.f, 0.f};
#pragma unroll
  for (int k = 0; k < TOPK; ++k) {
    ushortx8 v = *reinterpret_cast<const ushortx8*>(p_buf + ((size_t)t * TOPK + k) * HID + c0);
#pragma unroll
    for (int j = 0; j < 8; ++j) s[j] += bf2f(v[j]);
  }
  float* dst = out + (size_t)t * HID + c0;
  *reinterpret_cast<float4*>(dst) = make_float4(s[0], s[1], s[2], s[3]);
  *reinterpret_cast<float4*>(dst + 4) = make_float4(s[4], s[5], s[6], s[7]);
}

extern "C" void kernel_launch(void* const* d_in, const int* in_sizes, int n_in,
                              void* d_out, int out_size, void* d_ws, size_t ws_size,
                              hipStream_t stream) {
  const float* x      = (const float*)d_in[0];
  const float* gate_w = (const float*)d_in[1];
  const int*   qw1    = (const int*)d_in[2];
  const int*   qz1    = (const int*)d_in[3];
  const float* sc1    = (const float*)d_in[4];
  const int*   qw2    = (const int*)d_in[5];
  const int*   qz2    = (const int*)d_in[6];
  const float* sc2    = (const float*)d_in[7];
  float* out = (float*)d_out;

  // workspace layout (R3/R8-verified; p_buf aliases dqw1, dead after gemm1)
  char* ws = (char*)d_ws;
  int* counts           = (int*)(ws);                        // 256 B
  int* tok_list         = (int*)(ws + 256);                  // 512 KB
  int* hslot_list       = (int*)(ws + 524544);               // 512 KB
  float* cw_list        = (float*)(ws + 1048832);            // 512 KB
  unsigned short* h_buf = (unsigned short*)(ws + 1573120);   // 16.8 MB
  unsigned short* xbf   = (unsigned short*)(ws + 18350336);  // 4.2 MB
  unsigned short* dqw1  = (unsigned short*)(ws + 22544640);  // 67 MB
  unsigned short* dqw2  = (unsigned short*)(ws + 89653504);  // 67 MB
  unsigned short* p_buf = (unsigned short*)(ws + 22544640);  // 33.6 MB (aliases dqw1)

  hipMemsetAsync(counts, 0, 256, stream);

  routing_kernel<<<T_TOK, 256, 0, stream>>>(x, gate_w, counts, tok_list, hslot_list, cw_list, xbf);
  dequant_kernel<<<dim3(4096 / 16, 1024 / 64), 256, 0, stream>>>(qw1, qz1, sc1, dqw1, HID, 4096);
  dequant_kernel<<<dim3(8192 / 16, 512 / 64), 256, 0, stream>>>(qw2, qz2, sc2, dqw2, IMED, 8192);

  mfma_gemm1<<<dim3(IMED / 128, T_TOK / 64, EXP), 256, 0, stream>>>(
      xbf, dqw1, counts, tok_list, hslot_list, cw_list, h_buf);
  mfma_gemm2<<<dim3(HID / 128, T_TOK / 64, EXP), 256, 0, stream>>>(
      h_buf, dqw2, counts, hslot_list, p_buf);
  reduce_kernel<<<(T_TOK * HID / 8) / 256, 256, 0, stream>>>(p_buf, out);
}

// Round 11
// 312.425 us; speedup vs baseline: 1.2700x; 1.0280x over previous
//
#include <hip/hip_runtime.h>
#include <hip/hip_bf16.h>

#define T_TOK 2048
#define HID   1024
#define EXP   64
#define TOPK  8
#define IMED  512

typedef __bf16 bf16x8 __attribute__((ext_vector_type(8)));
typedef float f32x4 __attribute__((ext_vector_type(4)));
typedef unsigned short ushortx8 __attribute__((ext_vector_type(8)));
typedef unsigned short ushortx4 __attribute__((ext_vector_type(4)));

__constant__ int kShifts[8] = {0, 16, 4, 20, 8, 24, 12, 28};

__device__ __forceinline__ void async16(const void* g, void* l) {
  __builtin_amdgcn_global_load_lds((const __attribute__((address_space(1))) void*)g,
                                   (__attribute__((address_space(3))) void*)l, 16, 0, 0);
}

// round-to-nearest-even f32 -> bf16 bits
__device__ __forceinline__ unsigned short f2bf(float f) {
  unsigned u = __builtin_bit_cast(unsigned, f);
  unsigned r = (u + 0x7fffu + ((u >> 16) & 1u)) >> 16;
  return (unsigned short)r;
}

__device__ __forceinline__ float bf2f(unsigned short b) {
  unsigned u = ((unsigned)b) << 16;
  return __builtin_bit_cast(float, u);
}

// ---------------- Routing: 256 thr/token, LDS x-row, fused bf16 cast (verified R4/R8) ----------------
__global__ __launch_bounds__(256) void routing_kernel(
    const float* __restrict__ x, const float* __restrict__ gate_w,
    int* __restrict__ counts, int* __restrict__ tok_list,
    int* __restrict__ hslot_list, float* __restrict__ cw_list,
    unsigned short* __restrict__ xbf) {
  const int t = blockIdx.x;
  const int tid = threadIdx.x;
  __shared__ float xs[HID];
  __shared__ float part[64][4];

  float4 v = reinterpret_cast<const float4*>(x + (size_t)t * HID)[tid];
  reinterpret_cast<float4*>(xs)[tid] = v;
  ushortx4 o;
  o[0] = f2bf(v.x); o[1] = f2bf(v.y); o[2] = f2bf(v.z); o[3] = f2bf(v.w);
  *reinterpret_cast<ushortx4*>(xbf + (size_t)t * HID + tid * 4) = o;
  __syncthreads();

  const int e = tid >> 2, seg = tid & 3;
  const float4* gp = reinterpret_cast<const float4*>(gate_w + (size_t)e * HID);
  const float4* xp = reinterpret_cast<const float4*>(xs);
  float acc = 0.f;
#pragma unroll 8
  for (int i = 0; i < 64; ++i) {
    float4 a = xp[i * 4 + seg];
    float4 b = gp[i * 4 + seg];
    acc = fmaf(a.x, b.x, acc);
    acc = fmaf(a.y, b.y, acc);
    acc = fmaf(a.z, b.z, acc);
    acc = fmaf(a.w, b.w, acc);
  }
  part[e][seg] = acc;
  __syncthreads();

  if (tid < 64) {
    float4 p = reinterpret_cast<const float4*>(part)[tid];
    float lg = (p.x + p.y) + (p.z + p.w);

    float m = lg;
    for (int off = 32; off; off >>= 1) m = fmaxf(m, __shfl_xor(m, off));
    float pe = expf(lg - m);
    float s = pe;
    for (int off = 32; off; off >>= 1) s += __shfl_xor(s, off);
    float prob = pe / s;

    float pcur = prob;
    float myv = 0.f;
    int myi = -1;
    float tsum = 0.f;
    for (int k = 0; k < TOPK; ++k) {
      float vv = pcur;
      int idx = tid;
      for (int off = 32; off; off >>= 1) {
        float ov = __shfl_xor(vv, off);
        int oi = __shfl_xor(idx, off);
        if (ov > vv || (ov == vv && oi < idx)) { vv = ov; idx = oi; }
      }
      tsum += vv;
      if (tid == k) { myv = vv; myi = idx; }
      if (tid == idx) pcur = -1.f;
    }

    if (tid < TOPK) {
      float cw = myv / tsum;
      int ex = myi;
      int slot = atomicAdd(&counts[ex], 1);
      tok_list[ex * T_TOK + slot] = t;
      hslot_list[ex * T_TOK + slot] = t * TOPK + tid;
      cw_list[ex * T_TOK + slot] = cw;
    }
  }
}

// ---------------- AWQ dequant -> bf16, transposed to [n][k] (verified R2/R3/R8) ----------------
__global__ __launch_bounds__(256) void dequant_kernel(
    const int* __restrict__ qw, const int* __restrict__ qz,
    const float* __restrict__ sc, unsigned short* __restrict__ outw,
    int K, int C) {
  __shared__ unsigned short tile[128][72];
  const int kk = threadIdx.x & 63;
  const int cc4 = threadIdx.x >> 6;  // 0..3
  const int k = blockIdx.y * 64 + kk;
  const int c0 = blockIdx.x * 16 + cc4 * 4;
  const int g = k >> 7;
  const int N = C * 8;

  int4 q4 = *reinterpret_cast<const int4*>(qw + (size_t)k * C + c0);
  int4 z4 = *reinterpret_cast<const int4*>(qz + (size_t)g * C + c0);
  const float* sp = sc + (size_t)g * N + (size_t)c0 * 8;
  const int qs[4] = {q4.x, q4.y, q4.z, q4.w};
  const int zs[4] = {z4.x, z4.y, z4.z, z4.w};
#pragma unroll
  for (int it = 0; it < 4; ++it) {
    const unsigned q = (unsigned)qs[it];
    const unsigned z = (unsigned)zs[it];
    float4 s0 = *reinterpret_cast<const float4*>(sp + it * 8);
    float4 s1 = *reinterpret_cast<const float4*>(sp + it * 8 + 4);
    float sv[8] = {s0.x, s0.y, s0.z, s0.w, s1.x, s1.y, s1.z, s1.w};
#pragma unroll
    for (int j = 0; j < 8; ++j) {
      const int sh = kShifts[j];
      const float val = (float)((int)((q >> sh) & 15u) - (int)((z >> sh) & 15u));
      tile[(cc4 * 4 + it) * 8 + j][kk] = f2bf(val * sv[j]);
    }
  }
  __syncthreads();
  const size_t kbase = (size_t)blockIdx.y * 64;
#pragma unroll
  for (int it = 0; it < 4; ++it) {
    const int slot = threadIdx.x + 256 * it;
    const int row = slot >> 3, seg = slot & 7;
    const int n = blockIdx.x * 128 + row;
    *reinterpret_cast<ushortx8*>(outw + (size_t)n * K + kbase + seg * 8) =
        *reinterpret_cast<const ushortx8*>(&tile[row][seg * 8]);
  }
}

// ---------------- MFMA GEMM1, M64 x N64 tile (8 blocks/CU live), dbuf BK=32 ----------------
// h[hslot, i] = silu(x . w1^T) * cw.  Waves 2x2, wave tile 32x32, acc[2][2].
__global__ __launch_bounds__(256) void mfma_gemm1(
    const unsigned short* __restrict__ xbf, const unsigned short* __restrict__ dqw1,
    const int* __restrict__ counts, const int* __restrict__ tok_list,
    const int* __restrict__ hslot_list, const float* __restrict__ cw_list,
    unsigned short* __restrict__ h_buf) {
  const int e = blockIdx.z;
  const int n_e = counts[e];
  const int t0 = blockIdx.y * 64;
  if (t0 >= n_e) return;
  const int ntile = blockIdx.x;  // 0..7 (64 cols each)
  const int tid = threadIdx.x;
  const int wave = tid >> 6, lane = tid & 63;
  const int wm = wave & 1, wn = wave >> 1;

  __shared__ unsigned short As[2][64 * 32];  // 2 x 4KB
  __shared__ unsigned short Bs[2][64 * 32];  // 2 x 4KB (total 16KB)

  // staging: thread -> row tid>>2 (wave-uniform base + lane*16), byte col (tid&3)*16
  const int srow = wave * 16 + (lane >> 2);
  const int bcol = (lane & 3) * 16;
  const int ta = tok_list[e * T_TOK + min(t0 + srow, n_e - 1)];
  const char* ga = (const char*)(xbf + (size_t)ta * HID) + bcol;
  const int nb = e * IMED + ntile * 64 + srow;
  const char* gb = (const char*)(dqw1 + (size_t)nb * HID) + bcol;

  f32x4 acc[2][2];
#pragma unroll
  for (int i = 0; i < 2; ++i)
#pragma unroll
    for (int j = 0; j < 2; ++j) acc[i][j] = (f32x4){0.f, 0.f, 0.f, 0.f};

  const int fr = lane & 15, fq = lane >> 4;

  auto stage = [&](int b) {
    async16(ga, (char*)&As[b][0] + wave * 1024);
    async16(gb, (char*)&Bs[b][0] + wave * 1024);
    ga += 64; gb += 64;
  };

  stage(0);
  int p = 0;
  for (int k0 = 0; k0 < HID; k0 += 32) {
    __syncthreads();  // drains async into buf p
    if (k0 + 32 < HID) stage(p ^ 1);
    bf16x8 af[2], bfr[2];
#pragma unroll
    for (int i = 0; i < 2; ++i)
      af[i] = *reinterpret_cast<const bf16x8*>(&As[p][(wm * 32 + i * 16 + fr) * 32 + fq * 8]);
#pragma unroll
    for (int j = 0; j < 2; ++j)
      bfr[j] = *reinterpret_cast<const bf16x8*>(&Bs[p][(wn * 32 + j * 16 + fr) * 32 + fq * 8]);
#pragma unroll
    for (int i = 0; i < 2; ++i)
#pragma unroll
      for (int j = 0; j < 2; ++j)
        acc[i][j] = __builtin_amdgcn_mfma_f32_16x16x32_bf16(af[i], bfr[j], acc[i][j], 0, 0, 0);
    p ^= 1;
  }

  // epilogue: C/D map col = lane&15, row = (lane>>4)*4 + reg
#pragma unroll
  for (int i = 0; i < 2; ++i) {
#pragma unroll
    for (int r = 0; r < 4; ++r) {
      const int grow = t0 + wm * 32 + i * 16 + fq * 4 + r;
      if (grow < n_e) {
        const float cw = cw_list[e * T_TOK + grow];
        const int hs = hslot_list[e * T_TOK + grow];
        unsigned short* dst = h_buf + (size_t)hs * IMED + ntile * 64 + wn * 32 + fr;
#pragma unroll
        for (int j = 0; j < 2; ++j) {
          const float v = acc[i][j][r];
          dst[j * 16] = f2bf((v / (1.f + expf(-v))) * cw);
        }
      }
    }
  }
}

// ---------------- MFMA GEMM2, M64 x N64 tile, dbuf BK=32: p_buf = h . w2^T ----------------
__global__ __launch_bounds__(256) void mfma_gemm2(
    const unsigned short* __restrict__ h_buf, const unsigned short* __restrict__ dqw2,
    const int* __restrict__ counts, const int* __restrict__ hslot_list,
    unsigned short* __restrict__ p_buf) {
  const int e = blockIdx.z;
  const int n_e = counts[e];
  const int t0 = blockIdx.y * 64;
  if (t0 >= n_e) return;
  const int ntile = blockIdx.x;  // 0..15 (64 cols each)
  const int tid = threadIdx.x;
  const int wave = tid >> 6, lane = tid & 63;
  const int wm = wave & 1, wn = wave >> 1;

  __shared__ unsigned short As[2][64 * 32];
  __shared__ unsigned short Bs[2][64 * 32];

  const int srow = wave * 16 + (lane >> 2);
  const int bcol = (lane & 3) * 16;
  const int ha = hslot_list[e * T_TOK + min(t0 + srow, n_e - 1)];
  const char* ga = (const char*)(h_buf + (size_t)ha * IMED) + bcol;
  const int nb = e * HID + ntile * 64 + srow;
  const char* gb = (const char*)(dqw2 + (size_t)nb * IMED) + bcol;

  f32x4 acc[2][2];
#pragma unroll
  for (int i = 0; i < 2; ++i)
#pragma unroll
    for (int j = 0; j < 2; ++j) acc[i][j] = (f32x4){0.f, 0.f, 0.f, 0.f};

  const int fr = lane & 15, fq = lane >> 4;

  auto stage = [&](int b) {
    async16(ga, (char*)&As[b][0] + wave * 1024);
    async16(gb, (char*)&Bs[b][0] + wave * 1024);
    ga += 64; gb += 64;
  };

  stage(0);
  int p = 0;
  for (int k0 = 0; k0 < IMED; k0 += 32) {
    __syncthreads();
    if (k0 + 32 < IMED) stage(p ^ 1);
    bf16x8 af[2], bfr[2];
#pragma unroll
    for (int i = 0; i < 2; ++i)
      af[i] = *reinterpret_cast<const bf16x8*>(&As[p][(wm * 32 + i * 16 + fr) * 32 + fq * 8]);
#pragma unroll
    for (int j = 0; j < 2; ++j)
      bfr[j] = *reinterpret_cast<const bf16x8*>(&Bs[p][(wn * 32 + j * 16 + fr) * 32 + fq * 8]);
#pragma unroll
    for (int i = 0; i < 2; ++i)
#pragma unroll
      for (int j = 0; j < 2; ++j)
        acc[i][j] = __builtin_amdgcn_mfma_f32_16x16x32_bf16(af[i], bfr[j], acc[i][j], 0, 0, 0);
    p ^= 1;
  }

  // epilogue: plain bf16 partial stores (no atomics); every (hslot, col) written once
#pragma unroll
  for (int i = 0; i < 2; ++i) {
#pragma unroll
    for (int r = 0; r < 4; ++r) {
      const int grow = t0 + wm * 32 + i * 16 + fq * 4 + r;
      if (grow < n_e) {
        const int hs = hslot_list[e * T_TOK + grow];
        unsigned short* dst = p_buf + (size_t)hs * HID + ntile * 64 + wn * 32 + fr;
#pragma unroll
        for (int j = 0; j < 2; ++j) dst[j * 16] = f2bf(acc[i][j][r]);
      }
    }
  }
}

// ---------------- Reduce 8 partials per token -> out (fp32, verified R3/R8) ----------------
__global__ __launch_bounds__(256) void reduce_kernel(const unsigned short* __restrict__ p_buf,
                                                     float* __restrict__ out) {
  const int idx = blockIdx.x * 256 + threadIdx.x;
  const int t = idx >> 7;
  const int c0 = (idx & 127) * 8;
  float s[8] = {0.f, 0.f, 0.f, 0.f, 0.f, 0.f, 0.f, 0.f};
#pragma unroll
  for (int k = 0; k < TOPK; ++k) {
    ushortx8 v = *reinterpret_cast<const ushortx8*>(p_buf + ((size_t)t * TOPK + k) * HID + c0);
#pragma unroll
    for (int j = 0; j < 8; ++j) s[j] += bf2f(v[j]);
  }
  float* dst = out + (size_t)t * HID + c0;
  *reinterpret_cast<float4*>(dst) = make_float4(s[0], s[1], s[2], s[3]);
  *reinterpret_cast<float4*>(dst + 4) = make_float4(s[4], s[5], s[6], s[7]);
}

extern "C" void kernel_launch(void* const* d_in, const int* in_sizes, int n_in,
                              void* d_out, int out_size, void* d_ws, size_t ws_size,
                              hipStream_t stream) {
  const float* x      = (const float*)d_in[0];
  const float* gate_w = (const float*)d_in[1];
  const int*   qw1    = (const int*)d_in[2];
  const int*   qz1    = (const int*)d_in[3];
  const float* sc1    = (const float*)d_in[4];
  const int*   qw2    = (const int*)d_in[5];
  const int*   qz2    = (const int*)d_in[6];
  const float* sc2    = (const float*)d_in[7];
  float* out = (float*)d_out;

  // workspace layout (R3/R8-verified; p_buf aliases dqw1, dead after gemm1)
  char* ws = (char*)d_ws;
  int* counts           = (int*)(ws);                        // 256 B
  int* tok_list         = (int*)(ws + 256);                  // 512 KB
  int* hslot_list       = (int*)(ws + 524544);               // 512 KB
  float* cw_list        = (float*)(ws + 1048832);            // 512 KB
  unsigned short* h_buf = (unsigned short*)(ws + 1573120);   // 16.8 MB
  unsigned short* xbf   = (unsigned short*)(ws + 18350336);  // 4.2 MB
  unsigned short* dqw1  = (unsigned short*)(ws + 22544640);  // 67 MB
  unsigned short* dqw2  = (unsigned short*)(ws + 89653504);  // 67 MB
  unsigned short* p_buf = (unsigned short*)(ws + 22544640);  // 33.6 MB (aliases dqw1)

  hipMemsetAsync(counts, 0, 256, stream);

  routing_kernel<<<T_TOK, 256, 0, stream>>>(x, gate_w, counts, tok_list, hslot_list, cw_list, xbf);
  dequant_kernel<<<dim3(4096 / 16, 1024 / 64), 256, 0, stream>>>(qw1, qz1, sc1, dqw1, HID, 4096);
  dequant_kernel<<<dim3(8192 / 16, 512 / 64), 256, 0, stream>>>(qw2, qz2, sc2, dqw2, IMED, 8192);

  mfma_gemm1<<<dim3(IMED / 64, T_TOK / 64, EXP), 256, 0, stream>>>(
      xbf, dqw1, counts, tok_list, hslot_list, cw_list, h_buf);
  mfma_gemm2<<<dim3(HID / 64, T_TOK / 64, EXP), 256, 0, stream>>>(
      h_buf, dqw2, counts, hslot_list, p_buf);
  reduce_kernel<<<(T_TOK * HID / 8) / 256, 256, 0, stream>>>(p_buf, out);
}